// Round 4
// baseline (1021.457 us; speedup 1.0000x reference)
//
#include <hip/hip_runtime.h>
#include <stdint.h>
#include <stddef.h>

typedef __bf16 bf16;
typedef bf16 bf16x8 __attribute__((ext_vector_type(8)));
typedef float f32x4 __attribute__((ext_vector_type(4)));

#define M_DIM 16384
#define K_DIM 4096
#define N_DIM 4096
#define BM 128
#define BN 128
#define BK 64
#define NT_N (N_DIM / BN) /* 32 col-tiles */

// global -> LDS direct (16B/lane; LDS dest is wave-uniform base + lane*16)
__device__ __forceinline__ void gload_lds16(const bf16* g, bf16* l) {
  __builtin_amdgcn_global_load_lds(
      (__attribute__((address_space(1))) void*)g,
      (__attribute__((address_space(3))) void*)l,
      16, 0, 0);
}

// ---------------- kernel 1: fp32 -> bf16 convert (memory-bound) -----------
__global__ void cvt_f32_bf16(const float* __restrict__ in,
                             bf16* __restrict__ out, int n) {
  const int stride = gridDim.x * blockDim.x;
  const int n8 = n >> 3;
  for (int i = blockIdx.x * blockDim.x + threadIdx.x; i < n8; i += stride) {
    const float4* p = (const float4*)in + (size_t)i * 2;
    float4 a = p[0];
    float4 b = p[1];
    bf16x8 o;
    o[0] = (bf16)a.x; o[1] = (bf16)a.y; o[2] = (bf16)a.z; o[3] = (bf16)a.w;
    o[4] = (bf16)b.x; o[5] = (bf16)b.y; o[6] = (bf16)b.z; o[7] = (bf16)b.w;
    ((bf16x8*)out)[i] = o;
  }
}

// ------------- kernel 2: bf16 GEMM (x . W^T) + fused partial LSE ----------
// A: [rows][K] bf16 strip, B(=W): [N][K] bf16. Each block: 128x128 output
// tile; per-row (max, sum_exp) over its 128 cols -> part[global_row][tn].
__global__ void __launch_bounds__(256) gemm_lse(
    const bf16* __restrict__ A, const bf16* __restrict__ B,
    const float* __restrict__ bias, float2* __restrict__ part,
    int nblk, int mrow0) {
  __shared__ __align__(16) bf16 sA[BM * BK];
  __shared__ __align__(16) bf16 sB[BN * BK];

  // T1: bijective XCD swizzle (nblk % 8 == 0 always: nblk = strips*32).
  const int bid = blockIdx.x;
  const int swz = (bid & 7) * (nblk >> 3) + (bid >> 3);
  const int tm = swz / NT_N;
  const int tn = swz % NT_N;

  const int tid = threadIdx.x;
  const int wid = tid >> 6;
  const int lane = tid & 63;
  const int wr = wid >> 1, wc = wid & 1;  // 2x2 waves, 64x64 out each

  const bf16* Ab = A + (size_t)tm * BM * K_DIM;
  const bf16* Bb = B + (size_t)tn * BN * K_DIM;

  // staging: chunk q = it*256 + tid -> LDS bytes [q*16, q*16+16).
  // row r = q>>3, slot j = q&7; slot j holds GLOBAL 8-elem chunk (j ^ (r&7))
  // of row r (inverse-swizzled source; reads apply the same XOR). rule #21.
  const int r0 = tid >> 3;  // + it*32
  const int j0 = tid & 7;

  f32x4 acc[4][4] = {};

  for (int kt = 0; kt < K_DIM / BK; ++kt) {
    const bf16* ak = Ab + kt * BK;
    const bf16* bk = Bb + kt * BK;
#pragma unroll
    for (int it = 0; it < 4; ++it) {
      const int r = it * 32 + r0;
      const int jj = (j0 ^ (r & 7)) * 8;  // pre-swizzled source chunk
      gload_lds16(ak + (size_t)r * K_DIM + jj, &sA[it * 2048 + wid * 512]);
      gload_lds16(bk + (size_t)r * K_DIM + jj, &sB[it * 2048 + wid * 512]);
    }
    __syncthreads();  // compiler drains vmcnt before s_barrier

#pragma unroll
    for (int kk = 0; kk < 2; ++kk) {
      bf16x8 af[4], bfr[4];
      const int ch = (lane >> 4) + kk * 4;  // logical 8-elem k-chunk
#pragma unroll
      for (int mi = 0; mi < 4; ++mi) {
        const int row = wr * 64 + mi * 16 + (lane & 15);
        af[mi] = *(const bf16x8*)&sA[row * BK + ((ch ^ (row & 7)) * 8)];
      }
#pragma unroll
      for (int ni = 0; ni < 4; ++ni) {
        const int row = wc * 64 + ni * 16 + (lane & 15);
        bfr[ni] = *(const bf16x8*)&sB[row * BK + ((ch ^ (row & 7)) * 8)];
      }
#pragma unroll
      for (int mi = 0; mi < 4; ++mi)
#pragma unroll
        for (int ni = 0; ni < 4; ++ni)
          acc[mi][ni] = __builtin_amdgcn_mfma_f32_16x16x32_bf16(
              af[mi], bfr[ni], acc[mi][ni], 0, 0, 0);
    }
    __syncthreads();
  }

  // ---- epilogue: bias + per-row (max, sum exp) over this block's 128 cols
  // C/D layout (m89/m91): col = lane&15, row = (lane>>4)*4 + reg.
  float bv[4];
#pragma unroll
  for (int ni = 0; ni < 4; ++ni)
    bv[ni] = bias[tn * BN + wc * 64 + ni * 16 + (lane & 15)];

  float2* red = (float2*)sA;  // [2 (wc)][128 rows]; safe post-barrier reuse

#pragma unroll
  for (int mi = 0; mi < 4; ++mi) {
#pragma unroll
    for (int r = 0; r < 4; ++r) {
      float v0 = acc[mi][0][r] + bv[0];
      float v1 = acc[mi][1][r] + bv[1];
      float v2 = acc[mi][2][r] + bv[2];
      float v3 = acc[mi][3][r] + bv[3];
      float mx = fmaxf(fmaxf(v0, v1), fmaxf(v2, v3));
#pragma unroll
      for (int d = 1; d < 16; d <<= 1) mx = fmaxf(mx, __shfl_xor(mx, d, 64));
      float s = __expf(v0 - mx) + __expf(v1 - mx) +
                __expf(v2 - mx) + __expf(v3 - mx);
#pragma unroll
      for (int d = 1; d < 16; d <<= 1) s += __shfl_xor(s, d, 64);
      if ((lane & 15) == 0) {
        const int row = wr * 64 + mi * 16 + (lane >> 4) * 4 + r;
        red[wc * 128 + row] = make_float2(mx, s);
      }
    }
  }
  __syncthreads();

  if (tid < 128) {
    float2 p0 = red[tid];
    float2 p1 = red[128 + tid];
    float mx = fmaxf(p0.x, p1.x);
    float s = p0.y * __expf(p0.x - mx) + p1.y * __expf(p1.x - mx);
    part[(size_t)(mrow0 + tm * BM + tid) * NT_N + tn] = make_float2(mx, s);
  }
}

// ------------- kernel 3: merge partials -> lse -> activations -------------
__global__ void finalize_k(const float2* __restrict__ part,
                           float* __restrict__ out) {
  const int m = blockIdx.x * blockDim.x + threadIdx.x;
  if (m >= M_DIM) return;
  const float2* p = part + (size_t)m * NT_N;
  float mx = -3.4e38f, s = 0.f;
#pragma unroll 8
  for (int t = 0; t < NT_N; ++t) {
    float2 v = p[t];
    float nm = fmaxf(mx, v.x);
    s = s * __expf(mx - nm) + v.y * __expf(v.x - nm);
    mx = nm;
  }
  float y = mx + __logf(s);
  // LeakyReLU x2 (slope 0.01)
  y = (y >= 0.f) ? y : 0.01f * y;
  y = (y >= 0.f) ? y : 0.01f * y;
  // logistic GELU x2: x * sigmoid(1.702 x)
  y = y / (1.f + __expf(-1.702f * y));
  y = y / (1.f + __expf(-1.702f * y));
  out[m] = y;
}

extern "C" void kernel_launch(void* const* d_in, const int* in_sizes, int n_in,
                              void* d_out, int out_size, void* d_ws,
                              size_t ws_size, hipStream_t stream) {
  const float* x = (const float*)d_in[0];     // [M][K] fp32
  const float* w = (const float*)d_in[1];     // [N][K] fp32
  const float* bias = (const float*)d_in[2];  // [N] fp32
  float* out = (float*)d_out;                 // [M] fp32

  // ws layout: W bf16 (32MB) | partials (4MB) | x-strip bf16 (variable).
  bf16* wb = (bf16*)d_ws;
  float2* part = (float2*)(wb + (size_t)N_DIM * K_DIM);
  bf16* xb = (bf16*)(part + (size_t)M_DIM * NT_N);
  const size_t fixed_b = (size_t)N_DIM * K_DIM * 2 + (size_t)M_DIM * NT_N * 8;

  // largest power-of-two M-strip whose bf16 copy fits the leftover ws
  int strip = M_DIM;
  while (strip > 128 && fixed_b + (size_t)strip * K_DIM * 2 > ws_size)
    strip >>= 1;

  hipLaunchKernelGGL(cvt_f32_bf16, dim3(512), dim3(256), 0, stream,
                     w, wb, N_DIM * K_DIM);

  const int nblk = (strip / BM) * NT_N;  // multiple of 32 -> swizzle bijective
  for (int m0 = 0; m0 < M_DIM; m0 += strip) {
    hipLaunchKernelGGL(cvt_f32_bf16, dim3(2048), dim3(256), 0, stream,
                       x + (size_t)m0 * K_DIM, xb, strip * K_DIM);
    hipLaunchKernelGGL(gemm_lse, dim3(nblk), dim3(256), 0, stream,
                       xb, wb, bias, part, nblk, m0);
  }

  hipLaunchKernelGGL(finalize_k, dim3((M_DIM + 255) / 256), dim3(256), 0,
                     stream, part, out);
}